// Round 10
// baseline (148.558 us; speedup 1.0000x reference)
//
#include <hip/hip_runtime.h>

#define M_TOT 32768   // B*T = 64*512
#define T_LEN 512
#define NIN   256
#define NH    1024
#define NOUT  256

typedef __attribute__((ext_vector_type(8))) short bf16x8;
typedef __attribute__((ext_vector_type(4))) float f32x4;
typedef unsigned short u16;
typedef unsigned int u32;

__device__ inline float bf2f(u16 u) {
  union { float f; unsigned int i; } v; v.i = ((unsigned int)u) << 16; return v.f;
}
__device__ inline u16 f2bf(float f) {
  union { float f; unsigned int i; } v; v.f = f;
  unsigned int r = v.i + 0x7FFFu + ((v.i >> 16) & 1u);
  return (u16)(r >> 16);
}

__device__ inline void gload_lds16(const void* g, void* l) {
  __builtin_amdgcn_global_load_lds(
      (const __attribute__((address_space(1))) void*)g,
      (__attribute__((address_space(3))) void*)l, 16, 0, 0);
}

#define PACK8(pk, v0, v1, SC)                                                     \
  pk.u[0] = f2bf((SC) * v0.x); pk.u[1] = f2bf((SC) * v0.y);                       \
  pk.u[2] = f2bf((SC) * v0.z); pk.u[3] = f2bf((SC) * v0.w);                       \
  pk.u[4] = f2bf((SC) * v1.x); pk.u[5] = f2bf((SC) * v1.y);                       \
  pk.u[6] = f2bf((SC) * v1.z); pk.u[7] = f2bf((SC) * v1.w);

// ---------------- prep (vectorized x8): INz, WiT, Acat, Wall[:,512:768], Wob ----------------
__global__ __launch_bounds__(256) void prep(const float* __restrict__ inp,
                                            const float* __restrict__ Wi,
                                            const float* __restrict__ Wih,
                                            const float* __restrict__ Whh,
                                            const float* __restrict__ Wo,
                                            u16* __restrict__ INz, u16* __restrict__ WiT,
                                            u16* __restrict__ Acat, u16* __restrict__ Wall,
                                            u16* __restrict__ Wob) {
  const long gid = (long)blockIdx.x * blockDim.x + threadIdx.x;
  const long stride = (long)gridDim.x * blockDim.x;
  union { u16 u[8]; uint4 q; } pk;
  if (gid < 32) ((uint4*)INz)[gid] = make_uint4(0, 0, 0, 0);
  const long nv = (long)M_TOT * NIN / 8;
  for (long i = gid; i < nv; i += stride) {
    const float4* s = (const float4*)(inp + i * 8);
    float4 v0 = s[0], v1 = s[1];
    PACK8(pk, v0, v1, 1.0f);
    *(uint4*)(INz + 256 + i * 8) = pk.q;
  }
  for (long i = gid; i < 2048L * 1024 / 8; i += stride) {
    long j = i * 8, g = j >> 10, h = j & 1023;
    const float* s = (g < NH) ? (Wih + g * NH + h) : (Whh + (g - NH) * NH + h);
    float sc = (g < NH) ? 1.0f : 0.98f;
    float4 v0 = ((const float4*)s)[0], v1 = ((const float4*)s)[1];
    PACK8(pk, v0, v1, sc);
    *(uint4*)(Acat + j) = pk.q;
  }
  for (long i = gid; i < 256L * 1024; i += stride) {
    long it = i >> 10, h = i & 1023;
    WiT[i] = f2bf(Wi[h * NIN + it]);
  }
  for (long i = gid; i < 1024L * 256 / 8; i += stride) {
    long j = i * 8, g = j >> 8, k = j & 255;
    const float* s = Wi + g * NIN + k;
    float4 v0 = ((const float4*)s)[0], v1 = ((const float4*)s)[1];
    PACK8(pk, v0, v1, 1.0f);
    *(uint4*)(Wall + g * 768 + 512 + k) = pk.q;
  }
  for (long i = gid; i < 256L * 1024 / 8; i += stride) {
    long j = i * 8;
    float4 v0 = ((const float4*)(Wo + j))[0], v1 = ((const float4*)(Wo + j))[1];
    PACK8(pk, v0, v1, 1.0f);
    *(uint4*)(Wob + j) = pk.q;
  }
}

// ---------------- biasvec: b1[g]=bih+bhh+W_ih.bi ; b2[g]=0.98*W_hh.bi ----------------
__global__ __launch_bounds__(256) void biasvec(const float* __restrict__ Wih,
                                               const float* __restrict__ Whh,
                                               const float* __restrict__ bi,
                                               const float* __restrict__ bih,
                                               const float* __restrict__ bhh,
                                               float* __restrict__ bias1,
                                               float* __restrict__ bias2) {
  __shared__ float s1[256], s2[256];
  const int g = blockIdx.x, tid = threadIdx.x;
  float a1 = 0.f, a2 = 0.f;
#pragma unroll
  for (int q = 0; q < 4; q++) {
    int h = tid + q * 256;
    float bv = bi[h];
    a1 += Wih[(size_t)g * NH + h] * bv;
    a2 += Whh[(size_t)g * NH + h] * bv;
  }
  s1[tid] = a1; s2[tid] = a2;
  __syncthreads();
  for (int off = 128; off > 0; off >>= 1) {
    if (tid < off) { s1[tid] += s1[tid + off]; s2[tid] += s2[tid + off]; }
    __syncthreads();
  }
  if (tid == 0) {
    bias1[g] = s1[0] + bih[g] + bhh[g];
    bias2[g] = 0.98f * s2[0];
  }
}

// ---------------- wab: Wall[:,0:512] = [Wa | Wb], M=2048,N=256,K=1024 ----------------
__global__ __launch_bounds__(256) void wab(const u16* __restrict__ Acat,
                                           const u16* __restrict__ WiT,
                                           u16* __restrict__ Wall) {
  __shared__ __align__(16) u16 As[128 * 32];
  __shared__ __align__(16) u16 Bs[128 * 32];
  const int tid = threadIdx.x;
  const int r0 = blockIdx.x * 128, c0 = blockIdx.y * 128;
  const int lane = tid & 63, wave = tid >> 6;
  const int wm = wave >> 1, wn = wave & 1;
  const int lm = lane & 15, kq = lane >> 4;

  f32x4 acc[4][4] = {};
  for (int k0 = 0; k0 < NH; k0 += 32) {
#pragma unroll
    for (int rr = 0; rr < 2; rr++) {
      int c = tid + rr * 256;
      int row = c >> 2, col = (c & 3) * 8;
      gload_lds16(Acat + (size_t)(r0 + row) * NH + k0 + col, (char*)As + c * 16);
      gload_lds16(WiT + (size_t)(c0 + row) * NH + k0 + col, (char*)Bs + c * 16);
    }
    __syncthreads();
    bf16x8 a[4], b[4];
#pragma unroll
    for (int i = 0; i < 4; i++) {
      a[i] = *(const bf16x8*)&As[(wm * 64 + i * 16 + lm) * 32 + kq * 8];
      b[i] = *(const bf16x8*)&Bs[(wn * 64 + i * 16 + lm) * 32 + kq * 8];
    }
#pragma unroll
    for (int i = 0; i < 4; i++)
#pragma unroll
      for (int jn = 0; jn < 4; jn++)
        acc[i][jn] = __builtin_amdgcn_mfma_f32_16x16x32_bf16(a[i], b[jn], acc[i][jn], 0, 0, 0);
    __syncthreads();
  }
#pragma unroll
  for (int i = 0; i < 4; i++) {
    int grb = r0 + wm * 64 + i * 16 + kq * 4;
#pragma unroll
    for (int jn = 0; jn < 4; jn++) {
      int gc = c0 + wn * 64 + jn * 16 + lm;
#pragma unroll
      for (int j = 0; j < 4; j++) {
        int g = grb + j;
        size_t dst = (g < NH) ? ((size_t)g * 768 + gc)
                              : ((size_t)(g - NH) * 768 + 256 + gc);
        Wall[dst] = f2bf(acc[i][jn][j]);
      }
    }
  }
}

// ---- fusedQ: m201-style 8-wave 256x128, BK=64, 2 phases/K-tile, 3-buf LDS, 2-deep prefetch ----
// tiles 0-3: A=IN_t,   B=Wall[:,0:256]   -> accC
// tiles 4-7: A=IN_prev,B=Wall[:,256:512] -> accC
// tiles 8-11:A=IN_t,   B=Wall[:,512:768] -> accX
// Per phase: {ds_reads || gloads(t+2) -> barrier -> lgkm(0)+SB -> setprio(1) -> 16 MFMA
//             -> setprio(0) -> [vmcnt(6) at tile end] -> barrier}
// H = 0.98*(accX+bi) + 0.02*relu(accC + b1 [+ b2 if t!=0]) -> out0 f32
__global__ __launch_bounds__(512, 2) void fusedQ(const u16* __restrict__ INz,
                                                 const u16* __restrict__ Wall,
                                                 const float* __restrict__ bi,
                                                 const float* __restrict__ bias1,
                                                 const float* __restrict__ bias2,
                                                 float* __restrict__ out0) {
  __shared__ __align__(16) u16 As[3][256 * 64];   // 3 x 32 KB
  __shared__ __align__(16) u16 Bs[3][128 * 64];   // 3 x 16 KB  (total 144 KB)
  const int tid = threadIdx.x;
  // bijective XCD swizzle over 1024 blocks (128 per XCD)
  const int bid = blockIdx.x;
  const int s = (bid & 7) * 128 + (bid >> 3);
  const int r0 = (s >> 3) * 256, c0 = (s & 7) * 128;
  const int wave = tid >> 6, lane = tid & 63;
  const int wr = wave >> 2, wc = wave & 3;         // 2M x 4N waves?? -> no: see below
  // 4M x 2N wave grid, each wave 64x64:
  const int wrm = wave >> 1, wcn = wave & 1;
  const int lm = lane & 15, kq = lane >> 4;

  // stage geometry: A: 2048 chunks / 512 thr = 4 each; B: 1024 chunks = 2 each.
  const int rth = tid >> 3;                         // 0..63
  const int l = (tid & 7) ^ (rth & 7);              // logical k-chunk for this slot
  const u16* aT[4]; const u16* aP[4];
#pragma unroll
  for (int i = 0; i < 4; i++) {
    int r = i * 64 + rth;                           // 0..255
    aT[i] = INz + (size_t)(r0 + r + 1) * NIN + l * 8;
    const bool bnd = ((r0 & (T_LEN - 1)) == 0) && (r == 0);
    aP[i] = bnd ? (INz + l * 8) : (aT[i] - NIN);
  }
  const u16* bS[2];
#pragma unroll
  for (int i = 0; i < 2; i++) {
    int rb = i * 64 + rth;                          // 0..127
    bS[i] = Wall + (size_t)(c0 + rb) * 768 + l * 8;
  }
  const u32 dA = (u32)tid * 16;                     // + i*8192
  const u32 dB = (u32)tid * 16;

#define IS_A(bufi, i, KT)                                                         \
  gload_lds16(((KT) < 4) ? (aT[i] + (KT) * 64)                                    \
              : (((KT) < 8) ? (aP[i] + ((KT) - 4) * 64)                           \
                            : (aT[i] + ((KT) - 8) * 64)),                         \
              (char*)&As[bufi][0] + dA + (i) * 8192)
#define IS_B(bufi, i, KT)                                                         \
  gload_lds16(bS[i] + (KT) * 64, (char*)&Bs[bufi][0] + dB + (i) * 8192)
#define STAGE_ALL(bufi, KT)                                                       \
  {                                                                               \
    IS_A(bufi, 0, KT); IS_A(bufi, 1, KT); IS_A(bufi, 2, KT); IS_A(bufi, 3, KT);   \
    IS_B(bufi, 0, KT); IS_B(bufi, 1, KT);                                         \
  }
#define WAITV6 asm volatile("s_waitcnt vmcnt(6)" ::: "memory")
#define WAITV0 asm volatile("s_waitcnt vmcnt(0)" ::: "memory")
#define SB __builtin_amdgcn_sched_barrier(0)
#define WAITL0                                                                    \
  {                                                                               \
    asm volatile("s_waitcnt lgkmcnt(0)" ::: "memory");                            \
    __builtin_amdgcn_sched_barrier(0);                                            \
  }
#define RDA(mf, ks)                                                               \
  af[mf][ks] = *(const bf16x8*)(Ab + (wrm * 64 + (mf) * 16 + lm) * 128 +          \
                                ((((ks) * 4 + kq) ^ (lm & 7)) * 16))
#define RDB2(dst, nf)                                                             \
  {                                                                               \
    dst[0] = *(const bf16x8*)(Bb + (wcn * 64 + (nf) * 16 + lm) * 128 +            \
                              ((kq ^ (lm & 7)) * 16));                            \
    dst[1] = *(const bf16x8*)(Bb + (wcn * 64 + (nf) * 16 + lm) * 128 +            \
                              (((4 + kq) ^ (lm & 7)) * 16));                      \
  }
#define QUAD(ACC, nf, bp)                                                         \
  _Pragma("unroll") for (int mf = 0; mf < 4; mf++) {                              \
    ACC[mf][nf] = __builtin_amdgcn_mfma_f32_16x16x32_bf16(af[mf][0], bp[0],       \
                                                          ACC[mf][nf], 0, 0, 0);  \
    ACC[mf][nf] = __builtin_amdgcn_mfma_f32_16x16x32_bf16(af[mf][1], bp[1],       \
                                                          ACC[mf][nf], 0, 0, 0);  \
  }

  f32x4 accC[4][4] = {};
  f32x4 accX[4][4] = {};

  // prologue: stage tile 0 -> buf0, tile 1 -> buf1; wait tile 0; barrier
  STAGE_ALL(0, 0);
  STAGE_ALL(1, 1);
  WAITV6;
  __builtin_amdgcn_s_barrier();

#pragma unroll
  for (int t = 0; t < 12; t++) {
    const int cb = t % 3;            // current buffer
    const int nb = (t + 2) % 3;      // prefetch target
    const char* Ab = (const char*)&As[cb][0];
    const char* Bb = (const char*)&Bs[cb][0];
    bf16x8 af[4][2], b01[2], b11[2], b21[2], b31[2];

    // ---- phase 0: ds{8 af + 4 bf} || gload A(t+2) ----
#pragma unroll
    for (int mf = 0; mf < 4; mf++) { RDA(mf, 0); RDA(mf, 1); }
    RDB2(b01, 0); RDB2(b11, 1);
    if (t < 10) { IS_A(nb, 0, t + 2); IS_A(nb, 1, t + 2); IS_A(nb, 2, t + 2); IS_A(nb, 3, t + 2); }
    __builtin_amdgcn_s_barrier();
    WAITL0;
    __builtin_amdgcn_s_setprio(1);
    if (t < 8) { QUAD(accC, 0, b01) QUAD(accC, 1, b11) }
    else       { QUAD(accX, 0, b01) QUAD(accX, 1, b11) }
    __builtin_amdgcn_s_setprio(0);
    __builtin_amdgcn_s_barrier();

    // ---- phase 1: ds{4 bf} || gload B(t+2); tile-end counted vmcnt ----
    RDB2(b21, 2); RDB2(b31, 3);
    if (t < 10) { IS_B(nb, 0, t + 2); IS_B(nb, 1, t + 2); }
    __builtin_amdgcn_s_barrier();
    WAITL0;
    __builtin_amdgcn_s_setprio(1);
    if (t < 8) { QUAD(accC, 2, b21) QUAD(accC, 3, b31) }
    else       { QUAD(accX, 2, b21) QUAD(accX, 3, b31) }
    __builtin_amdgcn_s_setprio(0);
    if (t < 10) { WAITV6; } else if (t == 10) { WAITV0; }
    __builtin_amdgcn_s_barrier();
  }
#undef IS_A
#undef IS_B
#undef STAGE_ALL
#undef RDA
#undef RDB2
#undef QUAD

  // ---- epilogue ----
#pragma unroll
  for (int mf = 0; mf < 4; mf++) {
    int grb = r0 + wrm * 64 + mf * 16 + kq * 4;
#pragma unroll
    for (int nf = 0; nf < 4; nf++) {
      int gc = c0 + wcn * 64 + nf * 16 + lm;
      float b1 = bias1[gc], b2v = bias2[gc], biv = bi[gc];
#pragma unroll
      for (int j = 0; j < 4; j++) {
        int gr = grb + j;
        float bb2 = b1 + (((gr & (T_LEN - 1)) != 0) ? b2v : 0.0f);
        float cv = fmaxf(accC[mf][nf][j] + bb2, 0.0f);
        float x = accX[mf][nf][j] + biv;
        out0[(size_t)gr * NH + gc] = 0.98f * x + 0.02f * cv;
      }
    }
  }
}

// ---------------- GEMM3: OUT = H * Wo^T + bo  (A reg-staged f32->bf16) ----------------
__global__ __launch_bounds__(256) void gemm3(const float* __restrict__ H,
                                             const u16* __restrict__ Wob,
                                             const float* __restrict__ bo,
                                             float* __restrict__ out1) {
  __shared__ __align__(16) u16 As[128 * 32];
  __shared__ __align__(16) u16 Bs[128 * 32];
  const int tid = threadIdx.x;
  const int r0 = blockIdx.x * 128, c0 = blockIdx.y * 128;
  const int lane = tid & 63, wave = tid >> 6;
  const int wm = wave >> 1, wn = wave & 1;
  const int lm = lane & 15, kq = lane >> 4;

  f32x4 acc[4][4] = {};
  for (int k0 = 0; k0 < NH; k0 += 32) {
#pragma unroll
    for (int rr = 0; rr < 2; rr++) {
      int c = tid + rr * 256;
      int row = c >> 2, col = (c & 3) * 8;
      const float* src = H + (size_t)(r0 + row) * NH + k0 + col;
      float4 v0 = *(const float4*)src;
      float4 v1 = *(const float4*)(src + 4);
      union { u16 u[8]; uint4 q; } pk;
      PACK8(pk, v0, v1, 1.0f);
      *(uint4*)((char*)As + c * 16) = pk.q;
      gload_lds16(Wob + (size_t)(c0 + row) * NH + k0 + col, (char*)Bs + c * 16);
    }
    __syncthreads();
    bf16x8 a[4], b[4];
#pragma unroll
    for (int i = 0; i < 4; i++) {
      a[i] = *(const bf16x8*)&As[(wm * 64 + i * 16 + lm) * 32 + kq * 8];
      b[i] = *(const bf16x8*)&Bs[(wn * 64 + i * 16 + lm) * 32 + kq * 8];
    }
#pragma unroll
    for (int i = 0; i < 4; i++)
#pragma unroll
      for (int jn = 0; jn < 4; jn++)
        acc[i][jn] = __builtin_amdgcn_mfma_f32_16x16x32_bf16(a[i], b[jn], acc[i][jn], 0, 0, 0);
    __syncthreads();
  }
#pragma unroll
  for (int i = 0; i < 4; i++) {
    int grb = r0 + wm * 64 + i * 16 + kq * 4;
#pragma unroll
    for (int jn = 0; jn < 4; jn++) {
      int gc = c0 + wn * 64 + jn * 16 + lm;
      float bv = bo[gc];
#pragma unroll
      for (int j = 0; j < 4; j++)
        out1[(size_t)(grb + j) * NOUT + gc] = acc[i][jn][j] + bv;
    }
  }
}

extern "C" void kernel_launch(void* const* d_in, const int* in_sizes, int n_in,
                              void* d_out, int out_size, void* d_ws, size_t ws_size,
                              hipStream_t stream) {
  const float* inp = (const float*)d_in[0];
  const float* Wi  = (const float*)d_in[1];
  const float* bi  = (const float*)d_in[2];
  const float* Wih = (const float*)d_in[3];
  const float* bih = (const float*)d_in[4];
  const float* Whh = (const float*)d_in[5];
  const float* bhh = (const float*)d_in[6];
  const float* Wo  = (const float*)d_in[7];
  const float* bo  = (const float*)d_in[8];

  float* out0 = (float*)d_out;                       // hidden [32768,1024] f32
  float* out1 = out0 + (size_t)M_TOT * NH;           // output [32768,256]  f32

  char* ws = (char*)d_ws;
  u16* Acat = (u16*)ws;                              //  2048 x 1024 bf16 =  4,194,304 B
  u16* WiT  = (u16*)(ws + 4194304);                  //   256 x 1024 bf16 =    524,288 B
  u16* Wall = (u16*)(ws + 4718592);                  //  1024 x  768 bf16 =  1,572,864 B
  u16* Wob  = (u16*)(ws + 6291456);                  //   256 x 1024 bf16 =    524,288 B
  float* bias1 = (float*)(ws + 6815744);             //  1024 f32 = 4096 B
  float* bias2 = (float*)(ws + 6819840);             //  1024 f32 = 4096 B
  // total ws usage: 6,823,936 B
  // INz lives in the out1 region (33.5 MB >= 16.8 MB); dead before gemm3 writes out1.
  u16* INz = (u16*)out1;                             // [1+32768][256] bf16 = 16,777,728 B

  hipLaunchKernelGGL(prep, dim3(2048), dim3(256), 0, stream,
                     inp, Wi, Wih, Whh, Wo, INz, WiT, Acat, Wall, Wob);
  hipLaunchKernelGGL(wab, dim3(16, 2), dim3(256), 0, stream, Acat, WiT, Wall);
  hipLaunchKernelGGL(biasvec, dim3(1024), dim3(256), 0, stream,
                     Wih, Whh, bi, bih, bhh, bias1, bias2);
  hipLaunchKernelGGL(fusedQ, dim3(1024), dim3(512), 0, stream,
                     INz, Wall, bi, bias1, bias2, out0);
  hipLaunchKernelGGL(gemm3, dim3(256, 2), dim3(256), 0, stream, out0, Wob, bo, out1);
}

// Round 11
// 141.631 us; speedup vs baseline: 1.0489x; 1.0489x over previous
//
#include <hip/hip_runtime.h>

#define M_TOT 32768   // B*T = 64*512
#define T_LEN 512
#define NIN   256
#define NH    1024
#define NOUT  256

typedef __attribute__((ext_vector_type(8))) short bf16x8;
typedef __attribute__((ext_vector_type(4))) float f32x4;
typedef unsigned short u16;
typedef unsigned int u32;

__device__ inline float bf2f(u16 u) {
  union { float f; unsigned int i; } v; v.i = ((unsigned int)u) << 16; return v.f;
}
__device__ inline u16 f2bf(float f) {
  union { float f; unsigned int i; } v; v.f = f;
  unsigned int r = v.i + 0x7FFFu + ((v.i >> 16) & 1u);
  return (u16)(r >> 16);
}

__device__ inline void gload_lds16(const void* g, void* l) {
  __builtin_amdgcn_global_load_lds(
      (const __attribute__((address_space(1))) void*)g,
      (__attribute__((address_space(3))) void*)l, 16, 0, 0);
}

#define PACK8(pk, v0, v1, SC)                                                     \
  pk.u[0] = f2bf((SC) * v0.x); pk.u[1] = f2bf((SC) * v0.y);                       \
  pk.u[2] = f2bf((SC) * v0.z); pk.u[3] = f2bf((SC) * v0.w);                       \
  pk.u[4] = f2bf((SC) * v1.x); pk.u[5] = f2bf((SC) * v1.y);                       \
  pk.u[6] = f2bf((SC) * v1.z); pk.u[7] = f2bf((SC) * v1.w);

// ---------------- prep (vectorized x8): INz, WiT, Acat, Wall[:,512:768], Wob ----------------
__global__ __launch_bounds__(256) void prep(const float* __restrict__ inp,
                                            const float* __restrict__ Wi,
                                            const float* __restrict__ Wih,
                                            const float* __restrict__ Whh,
                                            const float* __restrict__ Wo,
                                            u16* __restrict__ INz, u16* __restrict__ WiT,
                                            u16* __restrict__ Acat, u16* __restrict__ Wall,
                                            u16* __restrict__ Wob) {
  const long gid = (long)blockIdx.x * blockDim.x + threadIdx.x;
  const long stride = (long)gridDim.x * blockDim.x;
  union { u16 u[8]; uint4 q; } pk;
  if (gid < 32) ((uint4*)INz)[gid] = make_uint4(0, 0, 0, 0);
  const long nv = (long)M_TOT * NIN / 8;
  for (long i = gid; i < nv; i += stride) {
    const float4* s = (const float4*)(inp + i * 8);
    float4 v0 = s[0], v1 = s[1];
    PACK8(pk, v0, v1, 1.0f);
    *(uint4*)(INz + 256 + i * 8) = pk.q;
  }
  for (long i = gid; i < 2048L * 1024 / 8; i += stride) {
    long j = i * 8, g = j >> 10, h = j & 1023;
    const float* s = (g < NH) ? (Wih + g * NH + h) : (Whh + (g - NH) * NH + h);
    float sc = (g < NH) ? 1.0f : 0.98f;
    float4 v0 = ((const float4*)s)[0], v1 = ((const float4*)s)[1];
    PACK8(pk, v0, v1, sc);
    *(uint4*)(Acat + j) = pk.q;
  }
  for (long i = gid; i < 256L * 1024; i += stride) {
    long it = i >> 10, h = i & 1023;
    WiT[i] = f2bf(Wi[h * NIN + it]);
  }
  for (long i = gid; i < 1024L * 256 / 8; i += stride) {
    long j = i * 8, g = j >> 8, k = j & 255;
    const float* s = Wi + g * NIN + k;
    float4 v0 = ((const float4*)s)[0], v1 = ((const float4*)s)[1];
    PACK8(pk, v0, v1, 1.0f);
    *(uint4*)(Wall + g * 768 + 512 + k) = pk.q;
  }
  for (long i = gid; i < 256L * 1024 / 8; i += stride) {
    long j = i * 8;
    float4 v0 = ((const float4*)(Wo + j))[0], v1 = ((const float4*)(Wo + j))[1];
    PACK8(pk, v0, v1, 1.0f);
    *(uint4*)(Wob + j) = pk.q;
  }
}

// ---------------- biasvec: b1[g]=bih+bhh+W_ih.bi ; b2[g]=0.98*W_hh.bi ----------------
__global__ __launch_bounds__(256) void biasvec(const float* __restrict__ Wih,
                                               const float* __restrict__ Whh,
                                               const float* __restrict__ bi,
                                               const float* __restrict__ bih,
                                               const float* __restrict__ bhh,
                                               float* __restrict__ bias1,
                                               float* __restrict__ bias2) {
  __shared__ float s1[256], s2[256];
  const int g = blockIdx.x, tid = threadIdx.x;
  float a1 = 0.f, a2 = 0.f;
#pragma unroll
  for (int q = 0; q < 4; q++) {
    int h = tid + q * 256;
    float bv = bi[h];
    a1 += Wih[(size_t)g * NH + h] * bv;
    a2 += Whh[(size_t)g * NH + h] * bv;
  }
  s1[tid] = a1; s2[tid] = a2;
  __syncthreads();
  for (int off = 128; off > 0; off >>= 1) {
    if (tid < off) { s1[tid] += s1[tid + off]; s2[tid] += s2[tid + off]; }
    __syncthreads();
  }
  if (tid == 0) {
    bias1[g] = s1[0] + bih[g] + bhh[g];
    bias2[g] = 0.98f * s2[0];
  }
}

// ---------------- wab: Wall[:,0:512] = [Wa | Wb], M=2048,N=256,K=1024 ----------------
__global__ __launch_bounds__(256) void wab(const u16* __restrict__ Acat,
                                           const u16* __restrict__ WiT,
                                           u16* __restrict__ Wall) {
  __shared__ __align__(16) u16 As[128 * 32];
  __shared__ __align__(16) u16 Bs[128 * 32];
  const int tid = threadIdx.x;
  const int r0 = blockIdx.x * 128, c0 = blockIdx.y * 128;
  const int lane = tid & 63, wave = tid >> 6;
  const int wm = wave >> 1, wn = wave & 1;
  const int lm = lane & 15, kq = lane >> 4;

  f32x4 acc[4][4] = {};
  for (int k0 = 0; k0 < NH; k0 += 32) {
#pragma unroll
    for (int rr = 0; rr < 2; rr++) {
      int c = tid + rr * 256;
      int row = c >> 2, col = (c & 3) * 8;
      gload_lds16(Acat + (size_t)(r0 + row) * NH + k0 + col, (char*)As + c * 16);
      gload_lds16(WiT + (size_t)(c0 + row) * NH + k0 + col, (char*)Bs + c * 16);
    }
    __syncthreads();
    bf16x8 a[4], b[4];
#pragma unroll
    for (int i = 0; i < 4; i++) {
      a[i] = *(const bf16x8*)&As[(wm * 64 + i * 16 + lm) * 32 + kq * 8];
      b[i] = *(const bf16x8*)&Bs[(wn * 64 + i * 16 + lm) * 32 + kq * 8];
    }
#pragma unroll
    for (int i = 0; i < 4; i++)
#pragma unroll
      for (int jn = 0; jn < 4; jn++)
        acc[i][jn] = __builtin_amdgcn_mfma_f32_16x16x32_bf16(a[i], b[jn], acc[i][jn], 0, 0, 0);
    __syncthreads();
  }
#pragma unroll
  for (int i = 0; i < 4; i++) {
    int grb = r0 + wm * 64 + i * 16 + kq * 4;
#pragma unroll
    for (int jn = 0; jn < 4; jn++) {
      int gc = c0 + wn * 64 + jn * 16 + lm;
#pragma unroll
      for (int j = 0; j < 4; j++) {
        int g = grb + j;
        size_t dst = (g < NH) ? ((size_t)g * 768 + gc)
                              : ((size_t)(g - NH) * 768 + 256 + gc);
        Wall[dst] = f2bf(acc[i][jn][j]);
      }
    }
  }
}

// ---- fused12 v3: round-8 geometry, but 8 waves/block (wave tile 64x32) for 4 waves/SIMD ----
// tiles 0-3: A=IN_t,   B=Wall[:,0:256]   -> accC
// tiles 4-7: A=IN_prev,B=Wall[:,256:512] -> accC
// tiles 8-11:A=IN_t,   B=Wall[:,512:768] -> accX
// Per tile: stage(t+1) 4 loads/thread; vmcnt(4); barrier; 12 ds_read; lgkm(0); 16 MFMA; barrier.
__global__ __launch_bounds__(512, 4) void fused12(const u16* __restrict__ INz,
                                                  const u16* __restrict__ Wall,
                                                  const float* __restrict__ bi,
                                                  const float* __restrict__ bias1,
                                                  const float* __restrict__ bias2,
                                                  float* __restrict__ out0) {
  __shared__ __align__(16) u16 As[2][128 * 64];   // 2 x 16 KB
  __shared__ __align__(16) u16 Bs[2][128 * 64];   // 2 x 16 KB  (total 64 KB, 2 blocks/CU)
  const int tid = threadIdx.x;
  const int bid = blockIdx.x;
  const int s = (bid & 7) * 256 + (bid >> 3);     // bijective XCD swizzle (2048 = 8*256)
  const int r0 = (s >> 3) * 128, c0 = (s & 7) * 128;
  const int wave = tid >> 6, lane = tid & 63;
  const int wrm = wave >> 2, wcn = wave & 3;      // 2M x 4N wave grid, 64x32 out each
  const int lm = lane & 15, kq = lane >> 4;

  // stage geometry: each panel = 1024 16B-chunks, 2 per thread (i=0,1 of 64 rows).
  const int rth = tid >> 3;                       // 0..63
  const int l = (tid & 7) ^ (rth & 7);            // logical k-chunk for this phys slot
  const u16* aT[2]; const u16* aP[2]; const u16* bS[2];
#pragma unroll
  for (int i = 0; i < 2; i++) {
    int r = i * 64 + rth;                         // 0..127
    aT[i] = INz + (size_t)(r0 + r + 1) * NIN + l * 8;
    const bool bnd = ((r0 & (T_LEN - 1)) == 0) && (r == 0);
    aP[i] = bnd ? (INz + l * 8) : (aT[i] - NIN);
    bS[i] = Wall + (size_t)(c0 + r) * 768 + l * 8;
  }
  const u32 dD = (u32)tid * 16;                   // + i*8192

#define IS_A(bufi, i, KT)                                                         \
  gload_lds16(((KT) < 4) ? (aT[i] + (KT) * 64)                                    \
              : (((KT) < 8) ? (aP[i] + ((KT) - 4) * 64)                           \
                            : (aT[i] + ((KT) - 8) * 64)),                         \
              (char*)&As[bufi][0] + dD + (i) * 8192)
#define IS_B(bufi, i, KT)                                                         \
  gload_lds16(bS[i] + (KT) * 64, (char*)&Bs[bufi][0] + dD + (i) * 8192)
#define STAGE(bufi, KT)                                                           \
  { IS_A(bufi, 0, KT); IS_A(bufi, 1, KT); IS_B(bufi, 0, KT); IS_B(bufi, 1, KT); }
#define WAITV4 asm volatile("s_waitcnt vmcnt(4)" ::: "memory")
#define WAITV0 asm volatile("s_waitcnt vmcnt(0)" ::: "memory")
#define WAITL0                                                                    \
  {                                                                               \
    asm volatile("s_waitcnt lgkmcnt(0)" ::: "memory");                            \
    __builtin_amdgcn_sched_barrier(0);                                            \
  }

  f32x4 accC[4][2] = {};
  f32x4 accX[4][2] = {};

  STAGE(0, 0);

#pragma unroll
  for (int t = 0; t < 12; t++) {
    if (t < 11) { STAGE((t + 1) & 1, t + 1); WAITV4; } else { WAITV0; }
    __builtin_amdgcn_s_barrier();     // buf[t&1] fully staged for all waves
    const char* Ab = (const char*)&As[t & 1][0];
    const char* Bb = (const char*)&Bs[t & 1][0];
    bf16x8 af[4][2], bf[2][2];
#pragma unroll
    for (int mf = 0; mf < 4; mf++)
#pragma unroll
      for (int ks = 0; ks < 2; ks++) {
        int row = wrm * 64 + mf * 16 + lm;
        int phys = (ks * 4 + kq) ^ (lm & 7);
        af[mf][ks] = *(const bf16x8*)(Ab + row * 128 + phys * 16);
      }
#pragma unroll
    for (int nf = 0; nf < 2; nf++)
#pragma unroll
      for (int ks = 0; ks < 2; ks++) {
        int row = wcn * 32 + nf * 16 + lm;
        int phys = (ks * 4 + kq) ^ (lm & 7);
        bf[nf][ks] = *(const bf16x8*)(Bb + row * 128 + phys * 16);
      }
    WAITL0;
    __builtin_amdgcn_s_setprio(1);
    if (t < 8) {
#pragma unroll
      for (int mf = 0; mf < 4; mf++)
#pragma unroll
        for (int nf = 0; nf < 2; nf++) {
          accC[mf][nf] = __builtin_amdgcn_mfma_f32_16x16x32_bf16(af[mf][0], bf[nf][0], accC[mf][nf], 0, 0, 0);
          accC[mf][nf] = __builtin_amdgcn_mfma_f32_16x16x32_bf16(af[mf][1], bf[nf][1], accC[mf][nf], 0, 0, 0);
        }
    } else {
#pragma unroll
      for (int mf = 0; mf < 4; mf++)
#pragma unroll
        for (int nf = 0; nf < 2; nf++) {
          accX[mf][nf] = __builtin_amdgcn_mfma_f32_16x16x32_bf16(af[mf][0], bf[nf][0], accX[mf][nf], 0, 0, 0);
          accX[mf][nf] = __builtin_amdgcn_mfma_f32_16x16x32_bf16(af[mf][1], bf[nf][1], accX[mf][nf], 0, 0, 0);
        }
    }
    __builtin_amdgcn_s_setprio(0);
    __builtin_amdgcn_s_barrier();     // all waves done reading buf[t&1]
  }
#undef IS_A
#undef IS_B
#undef STAGE

  // ---- epilogue ----
#pragma unroll
  for (int mf = 0; mf < 4; mf++) {
    int grb = r0 + wrm * 64 + mf * 16 + kq * 4;
#pragma unroll
    for (int nf = 0; nf < 2; nf++) {
      int gc = c0 + wcn * 32 + nf * 16 + lm;
      float b1 = bias1[gc], b2v = bias2[gc], biv = bi[gc];
#pragma unroll
      for (int j = 0; j < 4; j++) {
        int gr = grb + j;
        float bb2 = b1 + (((gr & (T_LEN - 1)) != 0) ? b2v : 0.0f);
        float cv = fmaxf(accC[mf][nf][j] + bb2, 0.0f);
        float x = accX[mf][nf][j] + biv;
        out0[(size_t)gr * NH + gc] = 0.98f * x + 0.02f * cv;
      }
    }
  }
}

// ---------------- GEMM3: OUT = H * Wo^T + bo  (A reg-staged f32->bf16) ----------------
__global__ __launch_bounds__(256) void gemm3(const float* __restrict__ H,
                                             const u16* __restrict__ Wob,
                                             const float* __restrict__ bo,
                                             float* __restrict__ out1) {
  __shared__ __align__(16) u16 As[128 * 32];
  __shared__ __align__(16) u16 Bs[128 * 32];
  const int tid = threadIdx.x;
  const int r0 = blockIdx.x * 128, c0 = blockIdx.y * 128;
  const int lane = tid & 63, wave = tid >> 6;
  const int wm = wave >> 1, wn = wave & 1;
  const int lm = lane & 15, kq = lane >> 4;

  f32x4 acc[4][4] = {};
  for (int k0 = 0; k0 < NH; k0 += 32) {
#pragma unroll
    for (int rr = 0; rr < 2; rr++) {
      int c = tid + rr * 256;
      int row = c >> 2, col = (c & 3) * 8;
      const float* src = H + (size_t)(r0 + row) * NH + k0 + col;
      float4 v0 = *(const float4*)src;
      float4 v1 = *(const float4*)(src + 4);
      union { u16 u[8]; uint4 q; } pk;
      PACK8(pk, v0, v1, 1.0f);
      *(uint4*)((char*)As + c * 16) = pk.q;
      gload_lds16(Wob + (size_t)(c0 + row) * NH + k0 + col, (char*)Bs + c * 16);
    }
    __syncthreads();
    bf16x8 a[4], b[4];
#pragma unroll
    for (int i = 0; i < 4; i++) {
      a[i] = *(const bf16x8*)&As[(wm * 64 + i * 16 + lm) * 32 + kq * 8];
      b[i] = *(const bf16x8*)&Bs[(wn * 64 + i * 16 + lm) * 32 + kq * 8];
    }
#pragma unroll
    for (int i = 0; i < 4; i++)
#pragma unroll
      for (int jn = 0; jn < 4; jn++)
        acc[i][jn] = __builtin_amdgcn_mfma_f32_16x16x32_bf16(a[i], b[jn], acc[i][jn], 0, 0, 0);
    __syncthreads();
  }
#pragma unroll
  for (int i = 0; i < 4; i++) {
    int grb = r0 + wm * 64 + i * 16 + kq * 4;
#pragma unroll
    for (int jn = 0; jn < 4; jn++) {
      int gc = c0 + wn * 64 + jn * 16 + lm;
      float bv = bo[gc];
#pragma unroll
      for (int j = 0; j < 4; j++)
        out1[(size_t)(grb + j) * NOUT + gc] = acc[i][jn][j] + bv;
    }
  }
}

extern "C" void kernel_launch(void* const* d_in, const int* in_sizes, int n_in,
                              void* d_out, int out_size, void* d_ws, size_t ws_size,
                              hipStream_t stream) {
  const float* inp = (const float*)d_in[0];
  const float* Wi  = (const float*)d_in[1];
  const float* bi  = (const float*)d_in[2];
  const float* Wih = (const float*)d_in[3];
  const float* bih = (const float*)d_in[4];
  const float* Whh = (const float*)d_in[5];
  const float* bhh = (const float*)d_in[6];
  const float* Wo  = (const float*)d_in[7];
  const float* bo  = (const float*)d_in[8];

  float* out0 = (float*)d_out;                       // hidden [32768,1024] f32
  float* out1 = out0 + (size_t)M_TOT * NH;           // output [32768,256]  f32

  char* ws = (char*)d_ws;
  u16* Acat = (u16*)ws;                              //  2048 x 1024 bf16 =  4,194,304 B
  u16* WiT  = (u16*)(ws + 4194304);                  //   256 x 1024 bf16 =    524,288 B
  u16* Wall = (u16*)(ws + 4718592);                  //  1024 x  768 bf16 =  1,572,864 B
  u16* Wob  = (u16*)(ws + 6291456);                  //   256 x 1024 bf16 =    524,288 B
  float* bias1 = (float*)(ws + 6815744);             //  1024 f32 = 4096 B
  float* bias2 = (float*)(ws + 6819840);             //  1024 f32 = 4096 B
  // total ws usage: 6,823,936 B
  // INz lives in the out1 region (33.5 MB >= 16.8 MB); dead before gemm3 writes out1.
  u16* INz = (u16*)out1;                             // [1+32768][256] bf16 = 16,777,728 B

  hipLaunchKernelGGL(prep, dim3(2048), dim3(256), 0, stream,
                     inp, Wi, Wih, Whh, Wo, INz, WiT, Acat, Wall, Wob);
  hipLaunchKernelGGL(wab, dim3(16, 2), dim3(256), 0, stream, Acat, WiT, Wall);
  hipLaunchKernelGGL(biasvec, dim3(1024), dim3(256), 0, stream,
                     Wih, Whh, bi, bih, bhh, bias1, bias2);
  hipLaunchKernelGGL(fused12, dim3(2048), dim3(512), 0, stream,
                     INz, Wall, bi, bias1, bias2, out0);
  hipLaunchKernelGGL(gemm3, dim3(256, 2), dim3(256), 0, stream, out0, Wob, bo, out1);
}

// Round 12
// 134.568 us; speedup vs baseline: 1.1040x; 1.0525x over previous
//
#include <hip/hip_runtime.h>

#define M_TOT 32768   // B*T = 64*512
#define T_LEN 512
#define NIN   256
#define NH    1024
#define NOUT  256

typedef __attribute__((ext_vector_type(8))) short bf16x8;
typedef __attribute__((ext_vector_type(4))) float f32x4;
typedef unsigned short u16;
typedef unsigned int u32;

__device__ inline float bf2f(u16 u) {
  union { float f; unsigned int i; } v; v.i = ((unsigned int)u) << 16; return v.f;
}
__device__ inline u16 f2bf(float f) {
  union { float f; unsigned int i; } v; v.f = f;
  unsigned int r = v.i + 0x7FFFu + ((v.i >> 16) & 1u);
  return (u16)(r >> 16);
}

__device__ inline void gload_lds16(const void* g, void* l) {
  __builtin_amdgcn_global_load_lds(
      (const __attribute__((address_space(1))) void*)g,
      (__attribute__((address_space(3))) void*)l, 16, 0, 0);
}

#define PACK8(pk, v0, v1, SC)                                                     \
  pk.u[0] = f2bf((SC) * v0.x); pk.u[1] = f2bf((SC) * v0.y);                       \
  pk.u[2] = f2bf((SC) * v0.z); pk.u[3] = f2bf((SC) * v0.w);                       \
  pk.u[4] = f2bf((SC) * v1.x); pk.u[5] = f2bf((SC) * v1.y);                       \
  pk.u[6] = f2bf((SC) * v1.z); pk.u[7] = f2bf((SC) * v1.w);

// ---------------- prep (vectorized x8): INz, WiT, Acat, Wall[:,512:768], Wob ----------------
__global__ __launch_bounds__(256) void prep(const float* __restrict__ inp,
                                            const float* __restrict__ Wi,
                                            const float* __restrict__ Wih,
                                            const float* __restrict__ Whh,
                                            const float* __restrict__ Wo,
                                            u16* __restrict__ INz, u16* __restrict__ WiT,
                                            u16* __restrict__ Acat, u16* __restrict__ Wall,
                                            u16* __restrict__ Wob) {
  const long gid = (long)blockIdx.x * blockDim.x + threadIdx.x;
  const long stride = (long)gridDim.x * blockDim.x;
  union { u16 u[8]; uint4 q; } pk;
  if (gid < 32) ((uint4*)INz)[gid] = make_uint4(0, 0, 0, 0);
  const long nv = (long)M_TOT * NIN / 8;
  for (long i = gid; i < nv; i += stride) {
    const float4* s = (const float4*)(inp + i * 8);
    float4 v0 = s[0], v1 = s[1];
    PACK8(pk, v0, v1, 1.0f);
    *(uint4*)(INz + 256 + i * 8) = pk.q;
  }
  for (long i = gid; i < 2048L * 1024 / 8; i += stride) {
    long j = i * 8, g = j >> 10, h = j & 1023;
    const float* s = (g < NH) ? (Wih + g * NH + h) : (Whh + (g - NH) * NH + h);
    float sc = (g < NH) ? 1.0f : 0.98f;
    float4 v0 = ((const float4*)s)[0], v1 = ((const float4*)s)[1];
    PACK8(pk, v0, v1, sc);
    *(uint4*)(Acat + j) = pk.q;
  }
  for (long i = gid; i < 256L * 1024; i += stride) {
    long it = i >> 10, h = i & 1023;
    WiT[i] = f2bf(Wi[h * NIN + it]);
  }
  for (long i = gid; i < 1024L * 256 / 8; i += stride) {
    long j = i * 8, g = j >> 8, k = j & 255;
    const float* s = Wi + g * NIN + k;
    float4 v0 = ((const float4*)s)[0], v1 = ((const float4*)s)[1];
    PACK8(pk, v0, v1, 1.0f);
    *(uint4*)(Wall + g * 768 + 512 + k) = pk.q;
  }
  for (long i = gid; i < 256L * 1024 / 8; i += stride) {
    long j = i * 8;
    float4 v0 = ((const float4*)(Wo + j))[0], v1 = ((const float4*)(Wo + j))[1];
    PACK8(pk, v0, v1, 1.0f);
    *(uint4*)(Wob + j) = pk.q;
  }
}

// ---------------- biasvec: b1[g]=bih+bhh+W_ih.bi ; b2[g]=0.98*W_hh.bi ----------------
__global__ __launch_bounds__(256) void biasvec(const float* __restrict__ Wih,
                                               const float* __restrict__ Whh,
                                               const float* __restrict__ bi,
                                               const float* __restrict__ bih,
                                               const float* __restrict__ bhh,
                                               float* __restrict__ bias1,
                                               float* __restrict__ bias2) {
  __shared__ float s1[256], s2[256];
  const int g = blockIdx.x, tid = threadIdx.x;
  float a1 = 0.f, a2 = 0.f;
#pragma unroll
  for (int q = 0; q < 4; q++) {
    int h = tid + q * 256;
    float bv = bi[h];
    a1 += Wih[(size_t)g * NH + h] * bv;
    a2 += Whh[(size_t)g * NH + h] * bv;
  }
  s1[tid] = a1; s2[tid] = a2;
  __syncthreads();
  for (int off = 128; off > 0; off >>= 1) {
    if (tid < off) { s1[tid] += s1[tid + off]; s2[tid] += s2[tid + off]; }
    __syncthreads();
  }
  if (tid == 0) {
    bias1[g] = s1[0] + bih[g] + bhh[g];
    bias2[g] = 0.98f * s2[0];
  }
}

// ---------------- wab: Wall[:,0:512] = [Wa | Wb], M=2048,N=256,K=1024 ----------------
__global__ __launch_bounds__(256) void wab(const u16* __restrict__ Acat,
                                           const u16* __restrict__ WiT,
                                           u16* __restrict__ Wall) {
  __shared__ __align__(16) u16 As[128 * 32];
  __shared__ __align__(16) u16 Bs[128 * 32];
  const int tid = threadIdx.x;
  const int r0 = blockIdx.x * 128, c0 = blockIdx.y * 128;
  const int lane = tid & 63, wave = tid >> 6;
  const int wm = wave >> 1, wn = wave & 1;
  const int lm = lane & 15, kq = lane >> 4;

  f32x4 acc[4][4] = {};
  for (int k0 = 0; k0 < NH; k0 += 32) {
#pragma unroll
    for (int rr = 0; rr < 2; rr++) {
      int c = tid + rr * 256;
      int row = c >> 2, col = (c & 3) * 8;
      gload_lds16(Acat + (size_t)(r0 + row) * NH + k0 + col, (char*)As + c * 16);
      gload_lds16(WiT + (size_t)(c0 + row) * NH + k0 + col, (char*)Bs + c * 16);
    }
    __syncthreads();
    bf16x8 a[4], b[4];
#pragma unroll
    for (int i = 0; i < 4; i++) {
      a[i] = *(const bf16x8*)&As[(wm * 64 + i * 16 + lm) * 32 + kq * 8];
      b[i] = *(const bf16x8*)&Bs[(wn * 64 + i * 16 + lm) * 32 + kq * 8];
    }
#pragma unroll
    for (int i = 0; i < 4; i++)
#pragma unroll
      for (int jn = 0; jn < 4; jn++)
        acc[i][jn] = __builtin_amdgcn_mfma_f32_16x16x32_bf16(a[i], b[jn], acc[i][jn], 0, 0, 0);
    __syncthreads();
  }
#pragma unroll
  for (int i = 0; i < 4; i++) {
    int grb = r0 + wm * 64 + i * 16 + kq * 4;
#pragma unroll
    for (int jn = 0; jn < 4; jn++) {
      int gc = c0 + wn * 64 + jn * 16 + lm;
#pragma unroll
      for (int j = 0; j < 4; j++) {
        int g = grb + j;
        size_t dst = (g < NH) ? ((size_t)g * 768 + gc)
                              : ((size_t)(g - NH) * 768 + 256 + gc);
        Wall[dst] = f2bf(acc[i][jn][j]);
      }
    }
  }
}

// ---- fused12 v4: A-frag register reuse across (Wa_p, Wi_p) tile pairs ----
// Tile order: Wa0,Wi0,Wa1,Wi1,Wa2,Wi2,Wa3,Wi3, Wb0,Wb1,Wb2,Wb3  (12 tiles)
//   even t<8 (Wa_p, p=t/2): stage; read 8 a-frags (KEEP in regs) + 8 b; 32 MFMA accC
//   odd  t<8 (Wi_p):        stage; read 8 b only (reuse a-frags); 32 MFMA accX
//   t>=8     (Wb_q):        stage; read 8 a (IN_prev) + 8 b;     32 MFMA accC
// A staged once per pair (8 A-stages vs 12). LDS reads 160/wave vs 192 (-17%).
// Counted vmcnt: B-only-stage tiles wait vmcnt(4); A+B-stage tiles vmcnt(8).
__global__ __launch_bounds__(256, 2) void fused12(const u16* __restrict__ INz,
                                                  const u16* __restrict__ Wall,
                                                  const float* __restrict__ bi,
                                                  const float* __restrict__ bias1,
                                                  const float* __restrict__ bias2,
                                                  float* __restrict__ out0) {
  __shared__ __align__(16) u16 As[2][128 * 64];   // 2 x 16 KB
  __shared__ __align__(16) u16 Bs[2][128 * 64];   // 2 x 16 KB  (total 64 KB, 2 blocks/CU)
  const int tid = threadIdx.x;
  const int bid = blockIdx.x;
  const int s = (bid & 7) * 256 + (bid >> 3);     // bijective XCD swizzle (2048 = 8*256)
  const int r0 = (s >> 3) * 128, c0 = (s & 7) * 128;
  const int wave = tid >> 6, lane = tid & 63;
  const int wrm = wave >> 1, wcn = wave & 1;      // 2x2 wave grid, 64x64 out each
  const int lm = lane & 15, kq = lane >> 4;

  // stage geometry: 1024 16B-chunks per panel, 4 per thread (groups i=0..3 of 32 rows).
  const int rr = tid >> 3;                        // 0..31
  const int l = (tid & 7) ^ (rr & 7);             // logical k-chunk for this phys slot
  const u16* aTb = INz + (size_t)(r0 + rr + 1) * NIN + l * 8;   // IN_t, group 0
  const bool bnd = ((r0 & (T_LEN - 1)) == 0) && (rr == 0);
  const u16* aP0 = bnd ? (INz + l * 8) : (aTb - NIN);           // IN_prev, group 0
  const u16* bb = Wall + (size_t)(c0 + rr) * 768 + l * 8;
  const u32 aD = (u32)tid * 16;

  // A-stage index sidx 0..7: sidx<4 -> IN_t chunk sidx ; sidx>=4 -> IN_prev chunk sidx-4
#define IS_A(bufi, i, SI)                                                         \
  gload_lds16(((SI) < 4) ? (aTb + (size_t)(i) * 32 * NIN + (SI) * 64)             \
              : (((i) == 0 ? aP0 : aTb + (size_t)(i) * 32 * NIN - NIN)            \
                 + ((SI) - 4) * 64),                                              \
              (char*)&As[bufi][0] + aD + (i) * 4096)
  // B col-offset per tile t: even t<8 -> (t/2)*64 (Wa); odd t<8 -> 512+(t/2)*64 (Wi);
  //                          t>=8 -> 256+(t-8)*64 (Wb)
#define BOFF(T) (((T) < 8) ? ((((T) & 1) ? 512 : 0) + ((T) / 2) * 64) : (256 + ((T) - 8) * 64))
#define IS_B(bufi, i, T)                                                          \
  gload_lds16(bb + (size_t)(i) * 32 * 768 + BOFF(T),                              \
              (char*)&Bs[bufi][0] + aD + (i) * 4096)
#define STAGE_A(bufi, SI) { IS_A(bufi, 0, SI); IS_A(bufi, 1, SI); IS_A(bufi, 2, SI); IS_A(bufi, 3, SI); }
#define STAGE_B(bufi, T)  { IS_B(bufi, 0, T); IS_B(bufi, 1, T); IS_B(bufi, 2, T); IS_B(bufi, 3, T); }
#define WAITV8 asm volatile("s_waitcnt vmcnt(8)" ::: "memory")
#define WAITV4 asm volatile("s_waitcnt vmcnt(4)" ::: "memory")
#define WAITV0 asm volatile("s_waitcnt vmcnt(0)" ::: "memory")
#define WAITL0                                                                    \
  {                                                                               \
    asm volatile("s_waitcnt lgkmcnt(0)" ::: "memory");                            \
    __builtin_amdgcn_sched_barrier(0);                                            \
  }

  f32x4 accC[4][4] = {};
  f32x4 accX[4][4] = {};
  bf16x8 af[4][2];                                // held across each (Wa,Wi) pair

  // prologue: A(0) -> Abuf0, B(0) -> Bbuf0
  STAGE_A(0, 0);
  STAGE_B(0, 0);

#pragma unroll
  for (int t = 0; t < 12; t++) {
    // s(t): A-stage index needed this tile; stage-ahead at the tile before it's used
    const int st = (t < 8) ? (t >> 1) : (t - 4);
    const int stn = (t + 1 < 8) ? ((t + 1) >> 1) : (t + 1 - 4);   // s(t+1)
    const bool stageA = (t < 11) && (stn != st);
    if (t < 11) STAGE_B((t + 1) & 1, t + 1);
    if (stageA) STAGE_A(stn & 1, stn);
    if (t == 11) { WAITV0; }
    else if (stageA) { WAITV8; }
    else { WAITV4; }
    __builtin_amdgcn_s_barrier();     // staged data for tile t visible to all waves
    const char* Ab = (const char*)&As[st & 1][0];
    const char* Bb = (const char*)&Bs[t & 1][0];
    const bool readA = (t >= 8) || ((t & 1) == 0);
    if (readA) {
#pragma unroll
      for (int mf = 0; mf < 4; mf++)
#pragma unroll
        for (int ks = 0; ks < 2; ks++) {
          int row = wrm * 64 + mf * 16 + lm;
          int phys = (ks * 4 + kq) ^ (lm & 7);
          af[mf][ks] = *(const bf16x8*)(Ab + row * 128 + phys * 16);
        }
    }
    bf16x8 bf[4][2];
#pragma unroll
    for (int nf = 0; nf < 4; nf++)
#pragma unroll
      for (int ks = 0; ks < 2; ks++) {
        int row = wcn * 64 + nf * 16 + lm;
        int phys = (ks * 4 + kq) ^ (lm & 7);
        bf[nf][ks] = *(const bf16x8*)(Bb + row * 128 + phys * 16);
      }
    WAITL0;
    __builtin_amdgcn_s_setprio(1);
    if ((t < 8) && (t & 1)) {
#pragma unroll
      for (int mf = 0; mf < 4; mf++)
#pragma unroll
        for (int nf = 0; nf < 4; nf++) {
          accX[mf][nf] = __builtin_amdgcn_mfma_f32_16x16x32_bf16(af[mf][0], bf[nf][0], accX[mf][nf], 0, 0, 0);
          accX[mf][nf] = __builtin_amdgcn_mfma_f32_16x16x32_bf16(af[mf][1], bf[nf][1], accX[mf][nf], 0, 0, 0);
        }
    } else {
#pragma unroll
      for (int mf = 0; mf < 4; mf++)
#pragma unroll
        for (int nf = 0; nf < 4; nf++) {
          accC[mf][nf] = __builtin_amdgcn_mfma_f32_16x16x32_bf16(af[mf][0], bf[nf][0], accC[mf][nf], 0, 0, 0);
          accC[mf][nf] = __builtin_amdgcn_mfma_f32_16x16x32_bf16(af[mf][1], bf[nf][1], accC[mf][nf], 0, 0, 0);
        }
    }
    __builtin_amdgcn_s_setprio(0);
    __builtin_amdgcn_s_barrier();     // all waves done reading this tile's buffers
  }
#undef IS_A
#undef IS_B
#undef BOFF
#undef STAGE_A
#undef STAGE_B

  // ---- epilogue ----
#pragma unroll
  for (int mf = 0; mf < 4; mf++) {
    int grb = r0 + wrm * 64 + mf * 16 + kq * 4;
#pragma unroll
    for (int nf = 0; nf < 4; nf++) {
      int gc = c0 + wcn * 64 + nf * 16 + lm;
      float b1 = bias1[gc], b2v = bias2[gc], biv = bi[gc];
#pragma unroll
      for (int j = 0; j < 4; j++) {
        int gr = grb + j;
        float bb2 = b1 + (((gr & (T_LEN - 1)) != 0) ? b2v : 0.0f);
        float cv = fmaxf(accC[mf][nf][j] + bb2, 0.0f);
        float x = accX[mf][nf][j] + biv;
        out0[(size_t)gr * NH + gc] = 0.98f * x + 0.02f * cv;
      }
    }
  }
}

// ---------------- GEMM3: OUT = H * Wo^T + bo  (A reg-staged f32->bf16) ----------------
__global__ __launch_bounds__(256) void gemm3(const float* __restrict__ H,
                                             const u16* __restrict__ Wob,
                                             const float* __restrict__ bo,
                                             float* __restrict__ out1) {
  __shared__ __align__(16) u16 As[128 * 32];
  __shared__ __align__(16) u16 Bs[128 * 32];
  const int tid = threadIdx.x;
  const int r0 = blockIdx.x * 128, c0 = blockIdx.y * 128;
  const int lane = tid & 63, wave = tid >> 6;
  const int wm = wave >> 1, wn = wave & 1;
  const int lm = lane & 15, kq = lane >> 4;

  f32x4 acc[4][4] = {};
  for (int k0 = 0; k0 < NH; k0 += 32) {
#pragma unroll
    for (int rr = 0; rr < 2; rr++) {
      int c = tid + rr * 256;
      int row = c >> 2, col = (c & 3) * 8;
      const float* src = H + (size_t)(r0 + row) * NH + k0 + col;
      float4 v0 = *(const float4*)src;
      float4 v1 = *(const float4*)(src + 4);
      union { u16 u[8]; uint4 q; } pk;
      PACK8(pk, v0, v1, 1.0f);
      *(uint4*)((char*)As + c * 16) = pk.q;
      gload_lds16(Wob + (size_t)(c0 + row) * NH + k0 + col, (char*)Bs + c * 16);
    }
    __syncthreads();
    bf16x8 a[4], b[4];
#pragma unroll
    for (int i = 0; i < 4; i++) {
      a[i] = *(const bf16x8*)&As[(wm * 64 + i * 16 + lm) * 32 + kq * 8];
      b[i] = *(const bf16x8*)&Bs[(wn * 64 + i * 16 + lm) * 32 + kq * 8];
    }
#pragma unroll
    for (int i = 0; i < 4; i++)
#pragma unroll
      for (int jn = 0; jn < 4; jn++)
        acc[i][jn] = __builtin_amdgcn_mfma_f32_16x16x32_bf16(a[i], b[jn], acc[i][jn], 0, 0, 0);
    __syncthreads();
  }
#pragma unroll
  for (int i = 0; i < 4; i++) {
    int grb = r0 + wm * 64 + i * 16 + kq * 4;
#pragma unroll
    for (int jn = 0; jn < 4; jn++) {
      int gc = c0 + wn * 64 + jn * 16 + lm;
      float bv = bo[gc];
#pragma unroll
      for (int j = 0; j < 4; j++)
        out1[(size_t)(grb + j) * NOUT + gc] = acc[i][jn][j] + bv;
    }
  }
}

extern "C" void kernel_launch(void* const* d_in, const int* in_sizes, int n_in,
                              void* d_out, int out_size, void* d_ws, size_t ws_size,
                              hipStream_t stream) {
  const float* inp = (const float*)d_in[0];
  const float* Wi  = (const float*)d_in[1];
  const float* bi  = (const float*)d_in[2];
  const float* Wih = (const float*)d_in[3];
  const float* bih = (const float*)d_in[4];
  const float* Whh = (const float*)d_in[5];
  const float* bhh = (const float*)d_in[6];
  const float* Wo  = (const float*)d_in[7];
  const float* bo  = (const float*)d_in[8];

  float* out0 = (float*)d_out;                       // hidden [32768,1024] f32
  float* out1 = out0 + (size_t)M_TOT * NH;           // output [32768,256]  f32

  char* ws = (char*)d_ws;
  u16* Acat = (u16*)ws;                              //  2048 x 1024 bf16 =  4,194,304 B
  u16* WiT  = (u16*)(ws + 4194304);                  //   256 x 1024 bf16 =    524,288 B
  u16* Wall = (u16*)(ws + 4718592);                  //  1024 x  768 bf16 =  1,572,864 B
  u16* Wob  = (u16*)(ws + 6291456);                  //   256 x 1024 bf16 =    524,288 B
  float* bias1 = (float*)(ws + 6815744);             //  1024 f32 = 4096 B
  float* bias2 = (float*)(ws + 6819840);             //  1024 f32 = 4096 B
  // total ws usage: 6,823,936 B
  // INz lives in the out1 region (33.5 MB >= 16.8 MB); dead before gemm3 writes out1.
  u16* INz = (u16*)out1;                             // [1+32768][256] bf16 = 16,777,728 B

  hipLaunchKernelGGL(prep, dim3(2048), dim3(256), 0, stream,
                     inp, Wi, Wih, Whh, Wo, INz, WiT, Acat, Wall, Wob);
  hipLaunchKernelGGL(wab, dim3(16, 2), dim3(256), 0, stream, Acat, WiT, Wall);
  hipLaunchKernelGGL(biasvec, dim3(1024), dim3(256), 0, stream,
                     Wih, Whh, bi, bih, bhh, bias1, bias2);
  hipLaunchKernelGGL(fused12, dim3(2048), dim3(256), 0, stream,
                     INz, Wall, bi, bias1, bias2, out0);
  hipLaunchKernelGGL(gemm3, dim3(256, 2), dim3(256), 0, stream, out0, Wob, bo, out1);
}

// Round 13
// 129.698 us; speedup vs baseline: 1.1454x; 1.0375x over previous
//
#include <hip/hip_runtime.h>

#define M_TOT 32768   // B*T = 64*512
#define T_LEN 512
#define NIN   256
#define NH    1024
#define NOUT  256

typedef __attribute__((ext_vector_type(8))) short bf16x8;
typedef __attribute__((ext_vector_type(4))) float f32x4;
typedef unsigned short u16;
typedef unsigned int u32;

__device__ inline float bf2f(u16 u) {
  union { float f; unsigned int i; } v; v.i = ((unsigned int)u) << 16; return v.f;
}
__device__ inline u16 f2bf(float f) {
  union { float f; unsigned int i; } v; v.f = f;
  unsigned int r = v.i + 0x7FFFu + ((v.i >> 16) & 1u);
  return (u16)(r >> 16);
}

__device__ inline void gload_lds16(const void* g, void* l) {
  __builtin_amdgcn_global_load_lds(
      (const __attribute__((address_space(1))) void*)g,
      (__attribute__((address_space(3))) void*)l, 16, 0, 0);
}

#define PACK8(pk, v0, v1, SC)                                                     \
  pk.u[0] = f2bf((SC) * v0.x); pk.u[1] = f2bf((SC) * v0.y);                       \
  pk.u[2] = f2bf((SC) * v0.z); pk.u[3] = f2bf((SC) * v0.w);                       \
  pk.u[4] = f2bf((SC) * v1.x); pk.u[5] = f2bf((SC) * v1.y);                       \
  pk.u[6] = f2bf((SC) * v1.z); pk.u[7] = f2bf((SC) * v1.w);

// ---------------- prep (vectorized x8): INz, WiT, Acat, Wall[:,512:768], Wob ----------------
__global__ __launch_bounds__(256) void prep(const float* __restrict__ inp,
                                            const float* __restrict__ Wi,
                                            const float* __restrict__ Wih,
                                            const float* __restrict__ Whh,
                                            const float* __restrict__ Wo,
                                            u16* __restrict__ INz, u16* __restrict__ WiT,
                                            u16* __restrict__ Acat, u16* __restrict__ Wall,
                                            u16* __restrict__ Wob) {
  const long gid = (long)blockIdx.x * blockDim.x + threadIdx.x;
  const long stride = (long)gridDim.x * blockDim.x;
  union { u16 u[8]; uint4 q; } pk;
  if (gid < 32) ((uint4*)INz)[gid] = make_uint4(0, 0, 0, 0);
  const long nv = (long)M_TOT * NIN / 8;
  for (long i = gid; i < nv; i += stride) {
    const float4* s = (const float4*)(inp + i * 8);
    float4 v0 = s[0], v1 = s[1];
    PACK8(pk, v0, v1, 1.0f);
    *(uint4*)(INz + 256 + i * 8) = pk.q;
  }
  for (long i = gid; i < 2048L * 1024 / 8; i += stride) {
    long j = i * 8, g = j >> 10, h = j & 1023;
    const float* s = (g < NH) ? (Wih + g * NH + h) : (Whh + (g - NH) * NH + h);
    float sc = (g < NH) ? 1.0f : 0.98f;
    float4 v0 = ((const float4*)s)[0], v1 = ((const float4*)s)[1];
    PACK8(pk, v0, v1, sc);
    *(uint4*)(Acat + j) = pk.q;
  }
  for (long i = gid; i < 256L * 1024; i += stride) {
    long it = i >> 10, h = i & 1023;
    WiT[i] = f2bf(Wi[h * NIN + it]);
  }
  for (long i = gid; i < 1024L * 256 / 8; i += stride) {
    long j = i * 8, g = j >> 8, k = j & 255;
    const float* s = Wi + g * NIN + k;
    float4 v0 = ((const float4*)s)[0], v1 = ((const float4*)s)[1];
    PACK8(pk, v0, v1, 1.0f);
    *(uint4*)(Wall + g * 768 + 512 + k) = pk.q;
  }
  for (long i = gid; i < 256L * 1024 / 8; i += stride) {
    long j = i * 8;
    float4 v0 = ((const float4*)(Wo + j))[0], v1 = ((const float4*)(Wo + j))[1];
    PACK8(pk, v0, v1, 1.0f);
    *(uint4*)(Wob + j) = pk.q;
  }
}

// ---------------- wabbias: blocks 0..31 = wab GEMM; blocks 32..1055 = biasvec ----------------
__global__ __launch_bounds__(256) void wabbias(const u16* __restrict__ Acat,
                                               const u16* __restrict__ WiT,
                                               u16* __restrict__ Wall,
                                               const float* __restrict__ Wih,
                                               const float* __restrict__ Whh,
                                               const float* __restrict__ bi,
                                               const float* __restrict__ bih,
                                               const float* __restrict__ bhh,
                                               float* __restrict__ bias1,
                                               float* __restrict__ bias2) {
  __shared__ __align__(16) u16 As[128 * 32];
  __shared__ __align__(16) u16 Bs[128 * 32];
  __shared__ float s1[256], s2[256];
  const int tid = threadIdx.x;
  if (blockIdx.x >= 32) {
    // ---- biasvec: b1[g]=bih+bhh+W_ih.bi ; b2[g]=0.98*W_hh.bi ----
    const int g = blockIdx.x - 32;
    float a1 = 0.f, a2 = 0.f;
#pragma unroll
    for (int q = 0; q < 4; q++) {
      int h = tid + q * 256;
      float bv = bi[h];
      a1 += Wih[(size_t)g * NH + h] * bv;
      a2 += Whh[(size_t)g * NH + h] * bv;
    }
    s1[tid] = a1; s2[tid] = a2;
    __syncthreads();
    for (int off = 128; off > 0; off >>= 1) {
      if (tid < off) { s1[tid] += s1[tid + off]; s2[tid] += s2[tid + off]; }
      __syncthreads();
    }
    if (tid == 0) {
      bias1[g] = s1[0] + bih[g] + bhh[g];
      bias2[g] = 0.98f * s2[0];
    }
    return;
  }
  // ---- wab: Wall[:,0:512] = [Wa | Wb], M=2048,N=256,K=1024 ----
  const int r0 = (blockIdx.x & 15) * 128, c0 = (blockIdx.x >> 4) * 128;
  const int lane = tid & 63, wave = tid >> 6;
  const int wm = wave >> 1, wn = wave & 1;
  const int lm = lane & 15, kq = lane >> 4;

  f32x4 acc[4][4] = {};
  for (int k0 = 0; k0 < NH; k0 += 32) {
#pragma unroll
    for (int rr = 0; rr < 2; rr++) {
      int c = tid + rr * 256;
      int row = c >> 2, col = (c & 3) * 8;
      gload_lds16(Acat + (size_t)(r0 + row) * NH + k0 + col, (char*)As + c * 16);
      gload_lds16(WiT + (size_t)(c0 + row) * NH + k0 + col, (char*)Bs + c * 16);
    }
    __syncthreads();
    bf16x8 a[4], b[4];
#pragma unroll
    for (int i = 0; i < 4; i++) {
      a[i] = *(const bf16x8*)&As[(wm * 64 + i * 16 + lm) * 32 + kq * 8];
      b[i] = *(const bf16x8*)&Bs[(wn * 64 + i * 16 + lm) * 32 + kq * 8];
    }
#pragma unroll
    for (int i = 0; i < 4; i++)
#pragma unroll
      for (int jn = 0; jn < 4; jn++)
        acc[i][jn] = __builtin_amdgcn_mfma_f32_16x16x32_bf16(a[i], b[jn], acc[i][jn], 0, 0, 0);
    __syncthreads();
  }
#pragma unroll
  for (int i = 0; i < 4; i++) {
    int grb = r0 + wm * 64 + i * 16 + kq * 4;
#pragma unroll
    for (int jn = 0; jn < 4; jn++) {
      int gc = c0 + wn * 64 + jn * 16 + lm;
#pragma unroll
      for (int j = 0; j < 4; j++) {
        int g = grb + j;
        size_t dst = (g < NH) ? ((size_t)g * 768 + gc)
                              : ((size_t)(g - NH) * 768 + 256 + gc);
        Wall[dst] = f2bf(acc[i][jn][j]);
      }
    }
  }
}

// ---- fused12 v5: shared A tile for IN_t AND IN_prev (row-shift reuse) ----
// Tile order: {Wa_p, Wi_p, Wb_p} for p=0..3 (12 tiles).
//   Wa_p: read a-frags from A[p&1] rows r (KEEP); b=Wall[:,p*64];     32 MFMA accC
//   Wi_p: reuse a-frags;                         b=Wall[:,512+p*64];  32 MFMA accX
//   Wb_p: read a-frags rows r-1 (row 0 from prologue regs / zeros);
//         b=Wall[:,256+p*64];                                        32 MFMA accC
// A staged 4x (only IN_t); IN_prev = same tile shifted one row. Counted vmcnt:
// t%3==0 && t<9: stage B+A -> vmcnt(8); t==11: vmcnt(0); else stage B -> vmcnt(4).
__global__ __launch_bounds__(256, 2) void fused12(const u16* __restrict__ INz,
                                                  const u16* __restrict__ Wall,
                                                  const float* __restrict__ bi,
                                                  const float* __restrict__ bias1,
                                                  const float* __restrict__ bias2,
                                                  float* __restrict__ out0) {
  __shared__ __align__(16) u16 As[2][128 * 64];   // 2 x 16 KB
  __shared__ __align__(16) u16 Bs[2][128 * 64];   // 2 x 16 KB  (total 64 KB, 2 blocks/CU)
  const int tid = threadIdx.x;
  const int bid = blockIdx.x;
  const int s = (bid & 7) * 256 + (bid >> 3);     // bijective XCD swizzle (2048 = 8*256)
  const int r0 = (s >> 3) * 128, c0 = (s & 7) * 128;
  const int wave = tid >> 6, lane = tid & 63;
  const int wrm = wave >> 1, wcn = wave & 1;      // 2x2 wave grid, 64x64 out each
  const int lm = lane & 15, kq = lane >> 4;

  // stage geometry: 1024 16B-chunks per panel, 4 per thread (groups i=0..3 of 32 rows).
  const int rr = tid >> 3;                        // 0..31
  const int l = (tid & 7) ^ (rr & 7);             // logical k-chunk for this phys slot
  const u16* aTb = INz + (size_t)(r0 + rr + 1) * NIN + l * 8;   // IN_t, group 0
  const u16* bb = Wall + (size_t)(c0 + rr) * 768 + l * 8;
  const u32 aD = (u32)tid * 16;

#define IS_A(bufi, i, P)                                                          \
  gload_lds16(aTb + (size_t)(i) * 32 * NIN + (P) * 64,                            \
              (char*)&As[bufi][0] + aD + (i) * 4096)
  // B col-offset per tile t: m=t%3, p=t/3: m0 -> p*64 (Wa); m1 -> 512+p*64 (Wi);
  //                                        m2 -> 256+p*64 (Wb)
#define BOFF(T) (((T) % 3 == 0) ? (((T) / 3) * 64)                                \
                : (((T) % 3 == 1) ? (512 + ((T) / 3) * 64) : (256 + ((T) / 3) * 64)))
#define IS_B(bufi, i, T)                                                          \
  gload_lds16(bb + (size_t)(i) * 32 * 768 + BOFF(T),                              \
              (char*)&Bs[bufi][0] + aD + (i) * 4096)
#define STAGE_A(bufi, P) { IS_A(bufi, 0, P); IS_A(bufi, 1, P); IS_A(bufi, 2, P); IS_A(bufi, 3, P); }
#define STAGE_B(bufi, T) { IS_B(bufi, 0, T); IS_B(bufi, 1, T); IS_B(bufi, 2, T); IS_B(bufi, 3, T); }
#define WAITV8 asm volatile("s_waitcnt vmcnt(8)" ::: "memory")
#define WAITV4 asm volatile("s_waitcnt vmcnt(4)" ::: "memory")
#define WAITV0 asm volatile("s_waitcnt vmcnt(0)" ::: "memory")
#define WAITL0                                                                    \
  {                                                                               \
    asm volatile("s_waitcnt lgkmcnt(0)" ::: "memory");                            \
    __builtin_amdgcn_sched_barrier(0);                                            \
  }

  f32x4 accC[4][4] = {};
  f32x4 accX[4][4] = {};
  bf16x8 af[4][2];                                // held across each p-group

  // ---- prologue: row0 frags (IN_prev row 0 of this block) then A(0), B(0) ----
  // These 8 loads are the OLDEST in the vmcnt queue -> covered by the first
  // counted wait; the compiler additionally inserts its own (weaker) waits.
  bf16x8 r0f[4][2];
  const bool zrow = ((r0 & (T_LEN - 1)) == 0);    // sequence boundary: row is zeros
#pragma unroll
  for (int p = 0; p < 4; p++)
#pragma unroll
    for (int ks = 0; ks < 2; ks++)
      r0f[p][ks] = *(const bf16x8*)(INz + (size_t)r0 * NIN + p * 64 + ks * 32 + kq * 8);
  STAGE_A(0, 0);
  STAGE_B(0, 0);

#pragma unroll
  for (int t = 0; t < 12; t++) {
    const int p = t / 3, m = t % 3;
    const int Ap = p & 1;
    // stage-ahead
    if (t < 11) STAGE_B((t + 1) & 1, t + 1);
    if (m == 0 && t < 9) STAGE_A((p + 1) & 1, p + 1);
    if (t == 11) { WAITV0; }
    else if (m == 0 && t < 9) { WAITV8; }
    else { WAITV4; }
    __builtin_amdgcn_s_barrier();     // staged data for tile t visible to all waves
    const char* Ab = (const char*)&As[Ap][0];
    const char* Bb = (const char*)&Bs[t & 1][0];
    if (m == 0) {
      // Wa: read & keep a-frags (rows r)
#pragma unroll
      for (int mf = 0; mf < 4; mf++)
#pragma unroll
        for (int ks = 0; ks < 2; ks++) {
          int row = wrm * 64 + mf * 16 + lm;
          int phys = (ks * 4 + kq) ^ (lm & 7);
          af[mf][ks] = *(const bf16x8*)(Ab + row * 128 + phys * 16);
        }
    } else if (m == 2) {
      // Wb: read a-frags at rows r-1 (clamp row 0; substitute r0f for lm==0)
#pragma unroll
      for (int mf = 0; mf < 4; mf++) {
        int r = wrm * 64 + mf * 16 + lm;
        int rb = (r == 0) ? 0 : (r - 1);
#pragma unroll
        for (int ks = 0; ks < 2; ks++) {
          int phys = (ks * 4 + kq) ^ (rb & 7);
          af[mf][ks] = *(const bf16x8*)(Ab + rb * 128 + phys * 16);
        }
      }
      if (wrm == 0) {
        bf16x8 z = {};
#pragma unroll
        for (int ks = 0; ks < 2; ks++) {
          bf16x8 sub = zrow ? z : r0f[p][ks];
          af[0][ks] = (lm == 0) ? sub : af[0][ks];
        }
      }
    }
    bf16x8 bf[4][2];
#pragma unroll
    for (int nf = 0; nf < 4; nf++)
#pragma unroll
      for (int ks = 0; ks < 2; ks++) {
        int row = wcn * 64 + nf * 16 + lm;
        int phys = (ks * 4 + kq) ^ (lm & 7);
        bf[nf][ks] = *(const bf16x8*)(Bb + row * 128 + phys * 16);
      }
    WAITL0;
    __builtin_amdgcn_s_setprio(1);
    if (m == 1) {
#pragma unroll
      for (int mf = 0; mf < 4; mf++)
#pragma unroll
        for (int nf = 0; nf < 4; nf++) {
          accX[mf][nf] = __builtin_amdgcn_mfma_f32_16x16x32_bf16(af[mf][0], bf[nf][0], accX[mf][nf], 0, 0, 0);
          accX[mf][nf] = __builtin_amdgcn_mfma_f32_16x16x32_bf16(af[mf][1], bf[nf][1], accX[mf][nf], 0, 0, 0);
        }
    } else {
#pragma unroll
      for (int mf = 0; mf < 4; mf++)
#pragma unroll
        for (int nf = 0; nf < 4; nf++) {
          accC[mf][nf] = __builtin_amdgcn_mfma_f32_16x16x32_bf16(af[mf][0], bf[nf][0], accC[mf][nf], 0, 0, 0);
          accC[mf][nf] = __builtin_amdgcn_mfma_f32_16x16x32_bf16(af[mf][1], bf[nf][1], accC[mf][nf], 0, 0, 0);
        }
    }
    __builtin_amdgcn_s_setprio(0);
    __builtin_amdgcn_s_barrier();     // all waves done reading this tile's buffers
  }
#undef IS_A
#undef IS_B
#undef BOFF
#undef STAGE_A
#undef STAGE_B

  // ---- epilogue ----
#pragma unroll
  for (int mf = 0; mf < 4; mf++) {
    int grb = r0 + wrm * 64 + mf * 16 + kq * 4;
#pragma unroll
    for (int nf = 0; nf < 4; nf++) {
      int gc = c0 + wcn * 64 + nf * 16 + lm;
      float b1 = bias1[gc], b2v = bias2[gc], biv = bi[gc];
#pragma unroll
      for (int j = 0; j < 4; j++) {
        int gr = grb + j;
        float bb2 = b1 + (((gr & (T_LEN - 1)) != 0) ? b2v : 0.0f);
        float cv = fmaxf(accC[mf][nf][j] + bb2, 0.0f);
        float x = accX[mf][nf][j] + biv;
        out0[(size_t)gr * NH + gc] = 0.98f * x + 0.02f * cv;
      }
    }
  }
}

// ---------------- GEMM3: OUT = H * Wo^T + bo  (A reg-staged f32->bf16) ----------------
__global__ __launch_bounds__(256) void gemm3(const float* __restrict__ H,
                                             const u16* __restrict__ Wob,
                                             const float* __restrict__ bo,
                                             float* __restrict__ out1) {
  __shared__ __align__(16) u16 As[128 * 32];
  __shared__ __align__(16) u16 Bs[128 * 32];
  const int tid = threadIdx.x;
  const int r0 = blockIdx.x * 128, c0 = blockIdx.y * 128;
  const int lane = tid & 63, wave = tid >> 6;
  const int wm = wave >> 1, wn = wave & 1;
  const int lm = lane & 15, kq = lane >> 4;

  f32x4 acc[4][4] = {};
  for (int k0 = 0; k0 < NH; k0 += 32) {
#pragma unroll
    for (int rr = 0; rr < 2; rr++) {
      int c = tid + rr * 256;
      int row = c >> 2, col = (c & 3) * 8;
      const float* src = H + (size_t)(r0 + row) * NH + k0 + col;
      float4 v0 = *(const float4*)src;
      float4 v1 = *(const float4*)(src + 4);
      union { u16 u[8]; uint4 q; } pk;
      PACK8(pk, v0, v1, 1.0f);
      *(uint4*)((char*)As + c * 16) = pk.q;
      gload_lds16(Wob + (size_t)(c0 + row) * NH + k0 + col, (char*)Bs + c * 16);
    }
    __syncthreads();
    bf16x8 a[4], b[4];
#pragma unroll
    for (int i = 0; i < 4; i++) {
      a[i] = *(const bf16x8*)&As[(wm * 64 + i * 16 + lm) * 32 + kq * 8];
      b[i] = *(const bf16x8*)&Bs[(wn * 64 + i * 16 + lm) * 32 + kq * 8];
    }
#pragma unroll
    for (int i = 0; i < 4; i++)
#pragma unroll
      for (int jn = 0; jn < 4; jn++)
        acc[i][jn] = __builtin_amdgcn_mfma_f32_16x16x32_bf16(a[i], b[jn], acc[i][jn], 0, 0, 0);
    __syncthreads();
  }
#pragma unroll
  for (int i = 0; i < 4; i++) {
    int grb = r0 + wm * 64 + i * 16 + kq * 4;
#pragma unroll
    for (int jn = 0; jn < 4; jn++) {
      int gc = c0 + wn * 64 + jn * 16 + lm;
      float bv = bo[gc];
#pragma unroll
      for (int j = 0; j < 4; j++)
        out1[(size_t)(grb + j) * NOUT + gc] = acc[i][jn][j] + bv;
    }
  }
}

extern "C" void kernel_launch(void* const* d_in, const int* in_sizes, int n_in,
                              void* d_out, int out_size, void* d_ws, size_t ws_size,
                              hipStream_t stream) {
  const float* inp = (const float*)d_in[0];
  const float* Wi  = (const float*)d_in[1];
  const float* bi  = (const float*)d_in[2];
  const float* Wih = (const float*)d_in[3];
  const float* bih = (const float*)d_in[4];
  const float* Whh = (const float*)d_in[5];
  const float* bhh = (const float*)d_in[6];
  const float* Wo  = (const float*)d_in[7];
  const float* bo  = (const float*)d_in[8];

  float* out0 = (float*)d_out;                       // hidden [32768,1024] f32
  float* out1 = out0 + (size_t)M_TOT * NH;           // output [32768,256]  f32

  char* ws = (char*)d_ws;
  u16* Acat = (u16*)ws;                              //  2048 x 1024 bf16 =  4,194,304 B
  u16* WiT  = (u16*)(ws + 4194304);                  //   256 x 1024 bf16 =    524,288 B
  u16* Wall = (u16*)(ws + 4718592);                  //  1024 x  768 bf16 =  1,572,864 B
  u16* Wob  = (u16*)(ws + 6291456);                  //   256 x 1024 bf16 =    524,288 B
  float* bias1 = (float*)(ws + 6815744);             //  1024 f32 = 4096 B
  float* bias2 = (float*)(ws + 6819840);             //  1024 f32 = 4096 B
  // total ws usage: 6,823,936 B
  // INz lives in the out1 region (33.5 MB >= 16.8 MB); dead before gemm3 writes out1.
  u16* INz = (u16*)out1;                             // [1+32768][256] bf16 = 16,777,728 B

  hipLaunchKernelGGL(prep, dim3(2048), dim3(256), 0, stream,
                     inp, Wi, Wih, Whh, Wo, INz, WiT, Acat, Wall, Wob);
  hipLaunchKernelGGL(wabbias, dim3(1056), dim3(256), 0, stream,
                     Acat, WiT, Wall, Wih, Whh, bi, bih, bhh, bias1, bias2);
  hipLaunchKernelGGL(fused12, dim3(2048), dim3(256), 0, stream,
                     INz, Wall, bi, bias1, bias2, out0);
  hipLaunchKernelGGL(gemm3, dim3(256, 2), dim3(256), 0, stream, out0, Wob, bo, out1);
}